// Round 1
// baseline (124.116 us; speedup 1.0000x reference)
//
#include <hip/hip_runtime.h>
#include <math.h>

// Problem constants (fixed by the reference setup)
constexpr int N = 4096;
constexpr int E = 128;
constexpr int H = 8;
constexpr int D = 16;      // E / H
constexpr int SPAN = 50;
constexpr int W = 2 * SPAN + 1;  // 101

// ---------------------------------------------------------------------------
// Kernel 1: fused projections  q = X@Wq+bq, k, v, and b = attn_bias@Wfe+bfe
// 128 threads/block (one thread per output column), 8 rows per block.
// W-matrix element loaded once per block, reused across 8 rows in registers.
// ---------------------------------------------------------------------------
__global__ __launch_bounds__(128) void proj_kernel(
    const float* __restrict__ query, const float* __restrict__ key,
    const float* __restrict__ value, const float* __restrict__ attn_bias,
    const float* __restrict__ Wq, const float* __restrict__ bq,
    const float* __restrict__ Wk, const float* __restrict__ bk,
    const float* __restrict__ Wv, const float* __restrict__ bv,
    const float* __restrict__ Wfe, const float* __restrict__ bfe,
    float* __restrict__ qo, float* __restrict__ ko,
    float* __restrict__ vo, float* __restrict__ bo_)
{
    constexpr int R = 8;
    __shared__ float xq[R][E];
    __shared__ float xk[R][E];
    __shared__ float xv[R][E];
    __shared__ float ab[R][H];

    const int t = threadIdx.x;
    const int row0 = blockIdx.x * R;

    #pragma unroll
    for (int r = 0; r < R; ++r) {
        xq[r][t] = query[(row0 + r) * E + t];
        xk[r][t] = key[(row0 + r) * E + t];
        xv[r][t] = value[(row0 + r) * E + t];
    }
    if (t < R * H) ab[t / H][t % H] = attn_bias[row0 * H + t];
    __syncthreads();

    float aq[R], ak[R], av[R], abf[R];
    const float vbq = bq[t], vbk = bk[t], vbv = bv[t], vbfe = bfe[t];
    #pragma unroll
    for (int r = 0; r < R; ++r) { aq[r] = vbq; ak[r] = vbk; av[r] = vbv; abf[r] = vbfe; }

    for (int kk = 0; kk < E; ++kk) {
        const float wq = Wq[kk * E + t];
        const float wk = Wk[kk * E + t];
        const float wv = Wv[kk * E + t];
        #pragma unroll
        for (int r = 0; r < R; ++r) {
            aq[r] = fmaf(xq[r][kk], wq, aq[r]);
            ak[r] = fmaf(xk[r][kk], wk, ak[r]);
            av[r] = fmaf(xv[r][kk], wv, av[r]);
        }
    }
    #pragma unroll
    for (int hh = 0; hh < H; ++hh) {
        const float wfe = Wfe[hh * E + t];
        #pragma unroll
        for (int r = 0; r < R; ++r) abf[r] = fmaf(ab[r][hh], wfe, abf[r]);
    }

    #pragma unroll
    for (int r = 0; r < R; ++r) {
        qo[(row0 + r) * E + t]  = aq[r];
        ko[(row0 + r) * E + t]  = ak[r];
        vo[(row0 + r) * E + t]  = av[r];
        bo_[(row0 + r) * E + t] = abf[r];
    }
}

// ---------------------------------------------------------------------------
// Kernel 2: banded attention. One wave (64 lanes) per (row, head) pair.
// Lanes cover window positions w = lane and w = lane + 64 (W = 101).
// Wave-wide shfl_xor reductions for max/sum; exp-weights staged in LDS;
// PV uses lane = (d, group) decomposition + 2-step shuffle reduce.
// ---------------------------------------------------------------------------
__global__ __launch_bounds__(256) void attn_kernel(
    const float* __restrict__ q, const float* __restrict__ k,
    const float* __restrict__ v, const float* __restrict__ b,
    float* __restrict__ attn)
{
    __shared__ float ew[4][104];   // per-wave exp weights (101 used)

    const int wave = threadIdx.x >> 6;
    const int lane = threadIdx.x & 63;
    const int wid  = blockIdx.x * 4 + wave;
    const int i = wid >> 3;        // row
    const int h = wid & 7;         // head

    const float* qp = q + i * E + h * D;
    const float* bp = b + i * E + h * D;

    float qa[D], ba[D];
    #pragma unroll
    for (int x = 0; x < 4; ++x) {
        const float4 t4 = reinterpret_cast<const float4*>(qp)[x];
        qa[4 * x + 0] = t4.x; qa[4 * x + 1] = t4.y;
        qa[4 * x + 2] = t4.z; qa[4 * x + 3] = t4.w;
        const float4 t5 = reinterpret_cast<const float4*>(bp)[x];
        ba[4 * x + 0] = t5.x; ba[4 * x + 1] = t5.y;
        ba[4 * x + 2] = t5.z; ba[4 * x + 3] = t5.w;
    }

    const float scale = 1.0f / 64.0f;   // 1/sqrt(4096)

    // scores for this lane's two window positions
    float s0 = -INFINITY, s1 = -INFINITY;
    const int j0 = i - SPAN + lane;
    const int j1 = j0 + 64;

    if (j0 >= 0 && j0 < N) {            // lane < 101 always (lane <= 63)
        const float* kp = k + j0 * E + h * D;
        const float* gp = b + j0 * E + h * D;
        float sq = 0.f, sb = 0.f;
        #pragma unroll
        for (int x = 0; x < 4; ++x) {
            const float4 kv = reinterpret_cast<const float4*>(kp)[x];
            const float4 gv = reinterpret_cast<const float4*>(gp)[x];
            sq = fmaf(qa[4*x+0], kv.x, sq); sq = fmaf(qa[4*x+1], kv.y, sq);
            sq = fmaf(qa[4*x+2], kv.z, sq); sq = fmaf(qa[4*x+3], kv.w, sq);
            sb = fmaf(ba[4*x+0], gv.x, sb); sb = fmaf(ba[4*x+1], gv.y, sb);
            sb = fmaf(ba[4*x+2], gv.z, sb); sb = fmaf(ba[4*x+3], gv.w, sb);
        }
        s0 = sq * scale + sb;
    }
    if (lane < W - 64 && j1 >= 0 && j1 < N) {
        const float* kp = k + j1 * E + h * D;
        const float* gp = b + j1 * E + h * D;
        float sq = 0.f, sb = 0.f;
        #pragma unroll
        for (int x = 0; x < 4; ++x) {
            const float4 kv = reinterpret_cast<const float4*>(kp)[x];
            const float4 gv = reinterpret_cast<const float4*>(gp)[x];
            sq = fmaf(qa[4*x+0], kv.x, sq); sq = fmaf(qa[4*x+1], kv.y, sq);
            sq = fmaf(qa[4*x+2], kv.z, sq); sq = fmaf(qa[4*x+3], kv.w, sq);
            sb = fmaf(ba[4*x+0], gv.x, sb); sb = fmaf(ba[4*x+1], gv.y, sb);
            sb = fmaf(ba[4*x+2], gv.z, sb); sb = fmaf(ba[4*x+3], gv.w, sb);
        }
        s1 = sq * scale + sb;
    }

    // wave-wide max
    float m = fmaxf(s0, s1);
    #pragma unroll
    for (int off = 32; off; off >>= 1) m = fmaxf(m, __shfl_xor(m, off));

    const float e0 = __expf(s0 - m);   // -inf -> 0
    const float e1 = __expf(s1 - m);

    float sum = e0 + e1;
    #pragma unroll
    for (int off = 32; off; off >>= 1) sum += __shfl_xor(sum, off);
    const float inv = 1.0f / sum;

    ew[wave][lane] = e0;
    if (lane < W - 64) ew[wave][64 + lane] = e1;
    __syncthreads();

    // PV: lane = (d, group); group g handles w = g, g+4, g+8, ...
    const int d = lane & 15;
    const int g = lane >> 4;
    float acc = 0.f;
    for (int w = g; w < W; w += 4) {
        const int j = i - SPAN + w;
        if (j >= 0 && j < N)
            acc = fmaf(ew[wave][w], v[j * E + h * D + d], acc);
    }
    acc += __shfl_xor(acc, 16);
    acc += __shfl_xor(acc, 32);

    if (lane < D) attn[i * E + h * D + lane] = acc * inv;
}

// ---------------------------------------------------------------------------
// Kernel 3: output projection  out = attn @ Wo + bo
// ---------------------------------------------------------------------------
__global__ __launch_bounds__(128) void out_kernel(
    const float* __restrict__ attn, const float* __restrict__ Wo,
    const float* __restrict__ bo, float* __restrict__ out)
{
    constexpr int R = 8;
    __shared__ float xa[R][E];

    const int t = threadIdx.x;
    const int row0 = blockIdx.x * R;

    #pragma unroll
    for (int r = 0; r < R; ++r)
        xa[r][t] = attn[(row0 + r) * E + t];
    __syncthreads();

    float acc[R];
    const float vb = bo[t];
    #pragma unroll
    for (int r = 0; r < R; ++r) acc[r] = vb;

    for (int kk = 0; kk < E; ++kk) {
        const float w = Wo[kk * E + t];
        #pragma unroll
        for (int r = 0; r < R; ++r) acc[r] = fmaf(xa[r][kk], w, acc[r]);
    }

    #pragma unroll
    for (int r = 0; r < R; ++r)
        out[(row0 + r) * E + t] = acc[r];
}

// ---------------------------------------------------------------------------
extern "C" void kernel_launch(void* const* d_in, const int* in_sizes, int n_in,
                              void* d_out, int out_size, void* d_ws, size_t ws_size,
                              hipStream_t stream) {
    const float* query     = (const float*)d_in[0];
    const float* key       = (const float*)d_in[1];
    const float* value     = (const float*)d_in[2];
    const float* attn_bias = (const float*)d_in[3];
    const float* Wq  = (const float*)d_in[4];
    const float* bq  = (const float*)d_in[5];
    const float* Wk  = (const float*)d_in[6];
    const float* bk  = (const float*)d_in[7];
    const float* Wv  = (const float*)d_in[8];
    const float* bv  = (const float*)d_in[9];
    const float* Wo  = (const float*)d_in[10];
    const float* bo  = (const float*)d_in[11];
    const float* Wfe = (const float*)d_in[12];
    const float* bfe = (const float*)d_in[13];

    float* ws = (float*)d_ws;
    const int NE = N * E;
    float* qw    = ws;
    float* kw    = ws + 1 * NE;
    float* vw    = ws + 2 * NE;
    float* bw    = ws + 3 * NE;
    float* attnw = ws + 4 * NE;

    proj_kernel<<<N / 8, 128, 0, stream>>>(query, key, value, attn_bias,
                                           Wq, bq, Wk, bk, Wv, bv, Wfe, bfe,
                                           qw, kw, vw, bw);
    attn_kernel<<<(N * H) / 4, 256, 0, stream>>>(qw, kw, vw, bw, attnw);
    out_kernel<<<N / 8, 128, 0, stream>>>(attnw, Wo, bo, (float*)d_out);
}

// Round 2
// 52.926 us; speedup vs baseline: 2.3451x; 2.3451x over previous
//
#include <hip/hip_runtime.h>
#include <math.h>

// Problem constants (fixed by the reference setup)
constexpr int N = 4096;
constexpr int E = 128;
constexpr int H = 8;
constexpr int D = 16;      // E / H
constexpr int SPAN = 50;
constexpr int W = 2 * SPAN + 1;  // 101

// ---------------------------------------------------------------------------
// Kernel 1: fused projections  q = X@Wq+bq, k, v, and b = attn_bias@Wfe+bfe
// 256 threads/block: half = tid>>7 handles 4 rows, col = tid&127.
// Block covers 8 rows -> grid 512 -> 2 blocks/CU (8 waves/CU).
// k-loop unrolled x4, x-tile read as float4 from LDS (wave-uniform broadcast).
// ---------------------------------------------------------------------------
__global__ __launch_bounds__(256) void proj_kernel(
    const float* __restrict__ query, const float* __restrict__ key,
    const float* __restrict__ value, const float* __restrict__ attn_bias,
    const float* __restrict__ Wq, const float* __restrict__ bq,
    const float* __restrict__ Wk, const float* __restrict__ bk,
    const float* __restrict__ Wv, const float* __restrict__ bv,
    const float* __restrict__ Wfe, const float* __restrict__ bfe,
    float* __restrict__ qo, float* __restrict__ ko,
    float* __restrict__ vo, float* __restrict__ bo_)
{
    __shared__ float xq[8][E];
    __shared__ float xk[8][E];
    __shared__ float xv[8][E];
    __shared__ float ab[8][H];

    const int tid  = threadIdx.x;
    const int col  = tid & 127;
    const int half = tid >> 7;
    const int row0 = blockIdx.x * 8;

    #pragma unroll
    for (int m = 0; m < 4; ++m) {
        const int e = tid + 256 * m;
        const int r = e >> 7, c = e & 127;
        xq[r][c] = query[(size_t)(row0 + r) * E + c];
        xk[r][c] = key  [(size_t)(row0 + r) * E + c];
        xv[r][c] = value[(size_t)(row0 + r) * E + c];
    }
    if (tid < 64) ab[tid >> 3][tid & 7] = attn_bias[(size_t)row0 * H + tid];
    __syncthreads();

    const int r0 = half * 4;
    float aq[4], ak[4], av[4], ai[4];
    {
        const float tq = bq[col], tk = bk[col], tv = bv[col], ti = bfe[col];
        #pragma unroll
        for (int r = 0; r < 4; ++r) { aq[r]=tq; ak[r]=tk; av[r]=tv; ai[r]=ti; }
    }

    for (int kk = 0; kk < E; kk += 4) {
        float wq[4], wk[4], wv[4];
        #pragma unroll
        for (int u = 0; u < 4; ++u) {
            wq[u] = Wq[(size_t)(kk + u) * E + col];
            wk[u] = Wk[(size_t)(kk + u) * E + col];
            wv[u] = Wv[(size_t)(kk + u) * E + col];
        }
        #pragma unroll
        for (int r = 0; r < 4; ++r) {
            float4 x;
            x = *(const float4*)&xq[r0 + r][kk];
            aq[r] = fmaf(x.x, wq[0], aq[r]); aq[r] = fmaf(x.y, wq[1], aq[r]);
            aq[r] = fmaf(x.z, wq[2], aq[r]); aq[r] = fmaf(x.w, wq[3], aq[r]);
            x = *(const float4*)&xk[r0 + r][kk];
            ak[r] = fmaf(x.x, wk[0], ak[r]); ak[r] = fmaf(x.y, wk[1], ak[r]);
            ak[r] = fmaf(x.z, wk[2], ak[r]); ak[r] = fmaf(x.w, wk[3], ak[r]);
            x = *(const float4*)&xv[r0 + r][kk];
            av[r] = fmaf(x.x, wv[0], av[r]); av[r] = fmaf(x.y, wv[1], av[r]);
            av[r] = fmaf(x.z, wv[2], av[r]); av[r] = fmaf(x.w, wv[3], av[r]);
        }
    }
    #pragma unroll
    for (int hh = 0; hh < H; ++hh) {
        const float wfe = Wfe[(size_t)hh * E + col];
        #pragma unroll
        for (int r = 0; r < 4; ++r)
            ai[r] = fmaf(ab[r0 + r][hh], wfe, ai[r]);
    }

    #pragma unroll
    for (int r = 0; r < 4; ++r) {
        const size_t o = (size_t)(row0 + r0 + r) * E + col;
        qo[o] = aq[r]; ko[o] = ak[r]; vo[o] = av[r]; bo_[o] = ai[r];
    }
}

// ---------------------------------------------------------------------------
// Kernel 2: banded attention. One 64-thread block per (8-row tile, head).
// Lane l holds K and B(feature) rows for absolute positions
//   p0 = i0-50+l  and  p1 = i0+14+l   (union of the 8 windows = 108 rows)
// in registers (64 VGPRs). Q/B query rows are wave-uniform -> scalar loads.
// V staged once in LDS (pad 17, conflict-free). Probs go through a 101-float
// LDS buffer for the transposed PV step (lane = (d, group-of-4)).
// ---------------------------------------------------------------------------
__global__ __launch_bounds__(64, 4) void attn_kernel(
    const float* __restrict__ q, const float* __restrict__ k,
    const float* __restrict__ v, const float* __restrict__ b,
    float* __restrict__ attn)
{
    __shared__ float vt[128][17];
    __shared__ float ew[104];

    const int lane = threadIdx.x;
    const int bid  = blockIdx.x;
    const int h    = bid & 7;
    const int i0   = (bid >> 3) * 8;
    const int base = i0 - SPAN;          // first row of the staged region

    // ---- stage V rows [base, base+128) into LDS ----
    #pragma unroll
    for (int rep = 0; rep < 2; ++rep) {
        const int r = rep * 64 + lane;
        int j = base + r;
        j = j < 0 ? 0 : (j > N - 1 ? N - 1 : j);
        const float4* vp = (const float4*)(v + (size_t)j * E + h * D);
        #pragma unroll
        for (int qt = 0; qt < 4; ++qt) {
            const float4 t = vp[qt];
            vt[r][qt * 4 + 0] = t.x; vt[r][qt * 4 + 1] = t.y;
            vt[r][qt * 4 + 2] = t.z; vt[r][qt * 4 + 3] = t.w;
        }
    }

    // ---- K/B(feature) rows for this lane's two positions -> registers ----
    const int p0 = base + lane;
    const int p1 = p0 + 64;
    const bool in0 = (p0 >= 0) && (p0 < N);
    const bool in1 = (p1 >= 0) && (p1 < N);
    const int c0 = p0 < 0 ? 0 : (p0 > N - 1 ? N - 1 : p0);
    const int c1 = p1 < 0 ? 0 : (p1 > N - 1 ? N - 1 : p1);

    float k0[16], k1[16], g0[16], g1[16];
    {
        const float4* kp0 = (const float4*)(k + (size_t)c0 * E + h * D);
        const float4* kp1 = (const float4*)(k + (size_t)c1 * E + h * D);
        const float4* gp0 = (const float4*)(b + (size_t)c0 * E + h * D);
        const float4* gp1 = (const float4*)(b + (size_t)c1 * E + h * D);
        #pragma unroll
        for (int x = 0; x < 4; ++x) {
            float4 t;
            t = kp0[x]; k0[4*x]=t.x; k0[4*x+1]=t.y; k0[4*x+2]=t.z; k0[4*x+3]=t.w;
            t = kp1[x]; k1[4*x]=t.x; k1[4*x+1]=t.y; k1[4*x+2]=t.z; k1[4*x+3]=t.w;
            t = gp0[x]; g0[4*x]=t.x; g0[4*x+1]=t.y; g0[4*x+2]=t.z; g0[4*x+3]=t.w;
            t = gp1[x]; g1[4*x]=t.x; g1[4*x+1]=t.y; g1[4*x+2]=t.z; g1[4*x+3]=t.w;
        }
    }
    __syncthreads();

    const float scale = 1.0f / 64.0f;    // 1/sqrt(4096)
    const int d = lane & 15;
    const int g = lane >> 4;

    for (int r = 0; r < 8; ++r) {
        // Q and B(query) for row i0+r: wave-uniform addresses -> scalar loads
        const float* qp = q + (size_t)(i0 + r) * E + h * D;
        const float* bp = b + (size_t)(i0 + r) * E + h * D;

        float sq0 = 0.f, sb0 = 0.f, sq1 = 0.f, sb1 = 0.f;
        #pragma unroll
        for (int x = 0; x < 16; ++x) {
            const float qv = qp[x];
            const float bv = bp[x];
            sq0 = fmaf(qv, k0[x], sq0);
            sq1 = fmaf(qv, k1[x], sq1);
            sb0 = fmaf(bv, g0[x], sb0);
            sb1 = fmaf(bv, g1[x], sb1);
        }
        // window membership: pos0 valid iff lane >= r, pos1 valid iff lane <= r+36
        const bool valid0 = in0 && (lane >= r);
        const bool valid1 = in1 && (lane <= r + 36);
        const float s0 = valid0 ? sq0 * scale + sb0 : -INFINITY;
        const float s1 = valid1 ? sq1 * scale + sb1 : -INFINITY;

        float m = fmaxf(s0, s1);
        #pragma unroll
        for (int off = 32; off; off >>= 1) m = fmaxf(m, __shfl_xor(m, off));

        const float e0 = __expf(s0 - m);   // -inf -> 0
        const float e1 = __expf(s1 - m);

        float sum = e0 + e1;
        #pragma unroll
        for (int off = 32; off; off >>= 1) sum += __shfl_xor(sum, off);
        const float inv = 1.0f / sum;

        // transpose probs to window coordinates: w0 = lane-r, w1 = 64+lane-r
        if (lane >= r)      ew[lane - r]      = e0;
        if (lane <= r + 36) ew[64 + lane - r] = e1;
        __syncthreads();

        // PV: lane = (d, g); group g covers w = g, g+4, ..., plus w=100 for g=0
        float acc = 0.f;
        #pragma unroll
        for (int it = 0; it < 25; ++it) {
            const int w = g + 4 * it;
            acc = fmaf(ew[w], vt[w + r][d], acc);
        }
        if (g == 0) acc = fmaf(ew[100], vt[100 + r][d], acc);

        acc += __shfl_xor(acc, 16);
        acc += __shfl_xor(acc, 32);

        if (lane < D) attn[(size_t)(i0 + r) * E + h * D + lane] = acc * inv;
        __syncthreads();
    }
}

// ---------------------------------------------------------------------------
// Kernel 3: output projection  out = attn @ Wo + bo  (same shape as proj)
// ---------------------------------------------------------------------------
__global__ __launch_bounds__(256) void out_kernel(
    const float* __restrict__ attn, const float* __restrict__ Wo,
    const float* __restrict__ bo, float* __restrict__ out)
{
    __shared__ float xa[8][E];

    const int tid  = threadIdx.x;
    const int col  = tid & 127;
    const int half = tid >> 7;
    const int row0 = blockIdx.x * 8;

    #pragma unroll
    for (int m = 0; m < 4; ++m) {
        const int e = tid + 256 * m;
        const int r = e >> 7, c = e & 127;
        xa[r][c] = attn[(size_t)(row0 + r) * E + c];
    }
    __syncthreads();

    const int r0 = half * 4;
    float acc[4];
    {
        const float t = bo[col];
        #pragma unroll
        for (int r = 0; r < 4; ++r) acc[r] = t;
    }

    for (int kk = 0; kk < E; kk += 4) {
        float w[4];
        #pragma unroll
        for (int u = 0; u < 4; ++u)
            w[u] = Wo[(size_t)(kk + u) * E + col];
        #pragma unroll
        for (int r = 0; r < 4; ++r) {
            const float4 x = *(const float4*)&xa[r0 + r][kk];
            acc[r] = fmaf(x.x, w[0], acc[r]); acc[r] = fmaf(x.y, w[1], acc[r]);
            acc[r] = fmaf(x.z, w[2], acc[r]); acc[r] = fmaf(x.w, w[3], acc[r]);
        }
    }

    #pragma unroll
    for (int r = 0; r < 4; ++r)
        out[(size_t)(row0 + r0 + r) * E + col] = acc[r];
}

// ---------------------------------------------------------------------------
extern "C" void kernel_launch(void* const* d_in, const int* in_sizes, int n_in,
                              void* d_out, int out_size, void* d_ws, size_t ws_size,
                              hipStream_t stream) {
    const float* query     = (const float*)d_in[0];
    const float* key       = (const float*)d_in[1];
    const float* value     = (const float*)d_in[2];
    const float* attn_bias = (const float*)d_in[3];
    const float* Wq  = (const float*)d_in[4];
    const float* bq  = (const float*)d_in[5];
    const float* Wk  = (const float*)d_in[6];
    const float* bk  = (const float*)d_in[7];
    const float* Wv  = (const float*)d_in[8];
    const float* bv  = (const float*)d_in[9];
    const float* Wo  = (const float*)d_in[10];
    const float* bo  = (const float*)d_in[11];
    const float* Wfe = (const float*)d_in[12];
    const float* bfe = (const float*)d_in[13];

    float* ws = (float*)d_ws;
    const int NE = N * E;
    float* qw    = ws;
    float* kw    = ws + 1 * NE;
    float* vw    = ws + 2 * NE;
    float* bw    = ws + 3 * NE;
    float* attnw = ws + 4 * NE;

    proj_kernel<<<N / 8, 256, 0, stream>>>(query, key, value, attn_bias,
                                           Wq, bq, Wk, bk, Wv, bv, Wfe, bfe,
                                           qw, kw, vw, bw);
    attn_kernel<<<(N / 8) * H, 64, 0, stream>>>(qw, kw, vw, bw, attnw);
    out_kernel<<<N / 8, 256, 0, stream>>>(attnw, Wo, bo, (float*)d_out);
}